// Round 5
// baseline (151.036 us; speedup 1.0000x reference)
//
#include <hip/hip_runtime.h>
#include <stdint.h>

#define IN_F 4096
#define OUT_F 4096
#define NG 32
#define NSTEP 32   // (K/2)/64 k-steps per half (in-block split-K)

typedef __attribute__((ext_vector_type(8))) _Float16 half8;
typedef __attribute__((ext_vector_type(2))) _Float16 half2t;
typedef __attribute__((ext_vector_type(4))) float floatx4;

// fp16 pack of (a,b) with RTZ — same op the old prep kernel used.
__device__ __forceinline__ unsigned pkh(float a, float b) {
  return __builtin_bit_cast(unsigned, __builtin_amdgcn_cvt_pkrtz(a, b));
}

// Magic-number nibble dequant: h = fp16(1024 + (q^8)); w = (h-(1032+zp))*s.
// Output pairs (n0,n4),(n1,n5),(n2,n6),(n3,n7) — matches pkh's (x_j, x_{j+4})
// A-side pairing, so MFMA k-slots stay consistent.
__device__ __forceinline__ uint4 dequant8(unsigned v, unsigned s2u, unsigned c2u) {
  unsigned tx = v ^ 0x88888888u;
  half2t s2 = __builtin_bit_cast(half2t, s2u);
  half2t c2 = __builtin_bit_cast(half2t, c2u);
  unsigned p0 = (tx & 0x000F000Fu) | 0x64006400u;
  unsigned p1 = ((tx >> 4) & 0x000F000Fu) | 0x64006400u;
  unsigned p2 = ((tx >> 8) & 0x000F000Fu) | 0x64006400u;
  unsigned p3 = ((tx >> 12) & 0x000F000Fu) | 0x64006400u;
  half2t w0 = (__builtin_bit_cast(half2t, p0) - c2) * s2;
  half2t w1 = (__builtin_bit_cast(half2t, p1) - c2) * s2;
  half2t w2 = (__builtin_bit_cast(half2t, p2) - c2) * s2;
  half2t w3 = (__builtin_bit_cast(half2t, p3) - c2) * s2;
  uint4 o;
  o.x = __builtin_bit_cast(unsigned, w0);
  o.y = __builtin_bit_cast(unsigned, w1);
  o.z = __builtin_bit_cast(unsigned, w2);
  o.w = __builtin_bit_cast(unsigned, w3);
  return o;
}

// Raw barrier: LDS-visibility only. No vmcnt drain — all global loads in this
// kernel target private registers (pure reg-staging), so in-flight vmem never
// needs to block the barrier; the compiler inserts counted vmcnt waits at the
// register consumers automatically.
__device__ __forceinline__ void sync_lds() {
  asm volatile("s_waitcnt lgkmcnt(0)" ::: "memory");
  __builtin_amdgcn_s_barrier();
}

// ---------------------------------------------------------------------------
// Single fused kernel: f32->fp16 convert (A), int4 dequant (B), GEMM, split-K
// reduce. C[m][n] = sum_k X[m][k] * W[n][k].
// 512 thr = 8 waves: waves 0-3 k in [0,2048), waves 4-7 k in [2048,4096);
// wave tile 64x64 (acc[4][4], 32 MFMA / k-step).
// Per k-step i: WRITE staged regs(i+1) -> LDS buf nxt; ISSUE loads(i+2);
// MFMA on buf cur; lgkmcnt(0)+s_barrier. Double-buffered LDS (128 KB, 1/CU).
// XOR chunk swizzle on ds_write addr + read addr (R4-verified involution).
// Grid (M/128, N/128): m-tiles vary fastest -> XCD round-robin pins each
// A-panel to one XCD's L2.
// ---------------------------------------------------------------------------
__global__ __launch_bounds__(512, 2) void gemm_fused(
    const float* __restrict__ X, const int* __restrict__ wp,
    const float* __restrict__ wscale, const int* __restrict__ wzero,
    float* __restrict__ out, int M, int N, int K) {
  __shared__ __align__(16) _Float16 Alds[4 * 8192];  // [half*2+buf][128*64] 64 KB
  __shared__ __align__(16) _Float16 Blds[4 * 8192];  // 64 KB

  const int t = threadIdx.x;
  const int wave = t >> 6, lane = t & 63;
  const int h = wave >> 2, w2 = wave & 3;
  const int wm = (w2 >> 1) * 64, wn = (w2 & 1) * 64;
  const int r = lane & 15, quad = lane >> 4, rb = r & 7;
  const int bm = blockIdx.x * 128, bn = blockIdx.y * 128;

  floatx4 acc[4][4] = {};

  // ---- A staging geometry: thread t covers row = t>>2, 16 f32 at kq*16 ----
  const int arow = t >> 2, kq = t & 3;
  const float* gX0 = X + (size_t)(bm + arow) * K + kq * 16;   // half0; half1 +2048
  const int aslot0 = arow * 64 + (((kq * 2 + 0) ^ (arow & 7)) << 3);
  const int aslot1 = arow * 64 + (((kq * 2 + 1) ^ (arow & 7)) << 3);

  // ---- B staging geometry: rows brow0, brow0+64; int32 slot kc8 ----
  const int brow0 = t >> 3, kc8 = t & 7;
  const int* gB0 = wp + (size_t)(bn + brow0) * (IN_F / 8) + kc8;
  const int* gB1 = wp + (size_t)(bn + brow0 + 64) * (IN_F / 8) + kc8;
  const float* gS0 = wscale + (size_t)(bn + brow0) * NG;
  const float* gS1 = wscale + (size_t)(bn + brow0 + 64) * NG;
  const int* gZ0 = wzero + (size_t)(bn + brow0) * NG;
  const int* gZ1 = wzero + (size_t)(bn + brow0 + 64) * NG;
  const int bslot0 = brow0 * 64 + ((kc8 ^ (brow0 & 7)) << 3);
  const int bslot1 = (brow0 + 64) * 64 + ((kc8 ^ (brow0 & 7)) << 3);

  // ---- staged registers (loaded step i-1, written to LDS step i) ----
  float4 ar[2][4];          // [half][4x float4] = 32 f32 of A
  unsigned bv[4];           // packed W: j = half*2 + rowhalf
  float bs[4];
  int bz[4];

  auto ISSUE = [&](int i) {
    const float* p0 = gX0 + i * 64;
#pragma unroll
    for (int q = 0; q < 4; ++q) ar[0][q] = ((const float4*)p0)[q];
    const float* p1 = p0 + 2048;
#pragma unroll
    for (int q = 0; q < 4; ++q) ar[1][q] = ((const float4*)p1)[q];
    bv[0] = (unsigned)gB0[i * 8];
    bv[1] = (unsigned)gB1[i * 8];
    bv[2] = (unsigned)gB0[i * 8 + 256];   // half1: +2048 fp16 = +256 int32
    bv[3] = (unsigned)gB1[i * 8 + 256];
    int g0 = i >> 1;                       // 128-group within half
    bs[0] = gS0[g0];      bz[0] = gZ0[g0];
    bs[1] = gS1[g0];      bz[1] = gZ1[g0];
    bs[2] = gS0[g0 + 16]; bz[2] = gZ0[g0 + 16];
    bs[3] = gS1[g0 + 16]; bz[3] = gZ1[g0 + 16];
  };

  auto WRITE = [&](int buf) {
    // A: convert 2x (16 f32 -> 2 uint4) per half, swizzled ds_write_b128.
#pragma unroll
    for (int hh = 0; hh < 2; ++hh) {
      uint4 u0, u1;
      u0.x = pkh(ar[hh][0].x, ar[hh][1].x);  // (x0,x4)
      u0.y = pkh(ar[hh][0].y, ar[hh][1].y);
      u0.z = pkh(ar[hh][0].z, ar[hh][1].z);
      u0.w = pkh(ar[hh][0].w, ar[hh][1].w);
      u1.x = pkh(ar[hh][2].x, ar[hh][3].x);
      u1.y = pkh(ar[hh][2].y, ar[hh][3].y);
      u1.z = pkh(ar[hh][2].z, ar[hh][3].z);
      u1.w = pkh(ar[hh][2].w, ar[hh][3].w);
      _Float16* base = &Alds[(hh * 2 + buf) * 8192];
      *(uint4*)&base[aslot0] = u0;
      *(uint4*)&base[aslot1] = u1;
    }
    // B: dequant + swizzled ds_write_b128.
#pragma unroll
    for (int j = 0; j < 4; ++j) {
      _Float16 sh = (_Float16)bs[j];
      _Float16 ch = (_Float16)(float)(1032 + bz[j]);  // exact in fp16
      unsigned s2 = (unsigned)__builtin_bit_cast(unsigned short, sh) * 0x10001u;
      unsigned c2 = (unsigned)__builtin_bit_cast(unsigned short, ch) * 0x10001u;
      int ofs = ((j >> 1) * 2 + buf) * 8192 + ((j & 1) ? bslot1 : bslot0);
      *(uint4*)&Blds[ofs] = dequant8(bv[j], s2, c2);
    }
  };

  // ---- prologue ----
  ISSUE(0);
  WRITE(0);       // compiler inserts counted vmcnt waits for the consumed regs
  ISSUE(1);
  sync_lds();

  int cur = 0;
  for (int i = 0; i < NSTEP; ++i) {
    const int nxt = cur ^ 1;
    if (i + 1 < NSTEP) {
      WRITE(nxt);                                    // data(i+1) -> other buffer
      ISSUE(i + 2 < NSTEP ? i + 2 : NSTEP - 1);      // loads ride across barrier
    }

    const _Float16* Ab = &Alds[(h * 2 + cur) * 8192];
    const _Float16* Bb = &Blds[(h * 2 + cur) * 8192];
#pragma unroll
    for (int ks = 0; ks < 2; ++ks) {
      half8 af[4], bf[4];
#pragma unroll
      for (int mi = 0; mi < 4; ++mi) {
        int R = wm + mi * 16 + r;                    // R&7 == rb
        af[mi] = *(const half8*)&Ab[R * 64 + (((ks * 4 + quad) ^ rb) << 3)];
      }
#pragma unroll
      for (int ni = 0; ni < 4; ++ni) {
        int R = wn + ni * 16 + r;
        bf[ni] = *(const half8*)&Bb[R * 64 + (((ks * 4 + quad) ^ rb) << 3)];
      }
#pragma unroll
      for (int mi = 0; mi < 4; ++mi)
#pragma unroll
        for (int ni = 0; ni < 4; ++ni)
          acc[mi][ni] = __builtin_amdgcn_mfma_f32_16x16x32_f16(
              af[mi], bf[ni], acc[mi][ni], 0, 0, 0);
    }
    sync_lds();   // lgkmcnt(0) + s_barrier: LDS visible, vmem stays in flight
    cur = nxt;
  }

  // ---- in-block split-K reduction (reuse A LDS region) ----
  floatx4* red = (floatx4*)Alds;
  if (h == 1) {
#pragma unroll
    for (int mi = 0; mi < 4; ++mi)
#pragma unroll
      for (int ni = 0; ni < 4; ++ni)
        red[(mi * 4 + ni) * 256 + w2 * 64 + lane] = acc[mi][ni];
  }
  __syncthreads();
  if (h == 0) {
#pragma unroll
    for (int mi = 0; mi < 4; ++mi) {
#pragma unroll
      for (int ni = 0; ni < 4; ++ni) {
        acc[mi][ni] += red[(mi * 4 + ni) * 256 + w2 * 64 + lane];
#pragma unroll
        for (int i = 0; i < 4; ++i) {
          int grow = bm + wm + mi * 16 + quad * 4 + i;
          int gcol = bn + wn + ni * 16 + r;
          out[(size_t)grow * N + gcol] = acc[mi][ni][i];
        }
      }
    }
  }
}

extern "C" void kernel_launch(void* const* d_in, const int* in_sizes, int n_in,
                              void* d_out, int out_size, void* d_ws, size_t ws_size,
                              hipStream_t stream) {
  const float* x = (const float*)d_in[0];
  const int* wp = (const int*)d_in[1];
  const float* wscale = (const float*)d_in[2];
  const int* wzero = (const int*)d_in[3];
  float* out = (float*)d_out;

  int M = in_sizes[0] / IN_F;  // 1024

  // Single kernel, no workspace. Grid: m-tiles fastest (XCD L2 locality for A).
  dim3 grid(M / 128, OUT_F / 128);   // (8, 32) = 256 blocks = 1/CU
  gemm_fused<<<grid, 512, 0, stream>>>(x, wp, wscale, wzero, out, M, OUT_F, IN_F);
}